// Round 1
// baseline (200.815 us; speedup 1.0000x reference)
//
#include <hip/hip_runtime.h>
#include <hip/hip_bf16.h>

#define KEHALF 7.199822675975274f
#define CUTOFF 12.0f

__global__ __launch_bounds__(256)
void damped_elec_kernel(const float* __restrict__ dist,
                        const float* __restrict__ vec,
                        const float* __restrict__ q,
                        const float* __restrict__ mu,
                        const float* __restrict__ quad,
                        const int* __restrict__ idx_u,
                        const int* __restrict__ idx_v,
                        float* __restrict__ out,
                        int E) {
    int t = blockIdx.x * blockDim.x + threadIdx.x;
    int e0 = t * 4;
    if (e0 >= E) return;

    if (e0 + 4 <= E) {
        // Vector path: 4 edges per thread.
        float dbuf[4];
        int ubuf[4], vbuf[4];
        float vv[12];
        *reinterpret_cast<float4*>(dbuf) = *reinterpret_cast<const float4*>(dist + e0);
        *reinterpret_cast<int4*>(ubuf)  = *reinterpret_cast<const int4*>(idx_u + e0);
        *reinterpret_cast<int4*>(vbuf)  = *reinterpret_cast<const int4*>(idx_v + e0);
        *reinterpret_cast<float4*>(vv)     = *reinterpret_cast<const float4*>(vec + 3 * e0);
        *reinterpret_cast<float4*>(vv + 4) = *reinterpret_cast<const float4*>(vec + 3 * e0 + 4);
        *reinterpret_cast<float4*>(vv + 8) = *reinterpret_cast<const float4*>(vec + 3 * e0 + 8);

        float res[4];
#pragma unroll
        for (int k = 0; k < 4; ++k) {
            float d = dbuf[k];
            int u = ubuf[k], v = vbuf[k];
            float vx = vv[3 * k + 0], vy = vv[3 * k + 1], vz = vv[3 * k + 2];

            float inv_d = 1.0f / d;
            float x = fminf(fmaxf(d * 0.5f, 0.0f), 1.0f);
            float x2 = x * x;
            float x3 = x2 * x;
            float sw = 1.0f - x3 * (10.0f - 15.0f * x + 6.0f * x2);
            float chi = sw / sqrtf(d * d + 1.0f) + (1.0f - sw) * inv_d;
            float chi2 = chi * chi;
            float chi3 = chi2 * chi;

            float qu = q[u], qv = q[v];
            const float* mu_u = mu + 3 * u;
            const float* mu_v = mu + 3 * v;
            float mux_u = mu_u[0], muy_u = mu_u[1], muz_u = mu_u[2];
            float mux_v = mu_v[0], muy_v = mu_v[1], muz_v = mu_v[2];

            float dot_uv = (vx * mux_v + vy * muy_v + vz * muz_v) * inv_d;
            float dot_vu = (vx * mux_u + vy * muy_u + vz * muz_u) * inv_d;
            float mudot  = mux_u * mux_v + muy_u * muy_v + muz_u * muz_v;

            float Eelec = qu * qv * chi
                        + 2.0f * qu * dot_uv * chi2
                        + (mudot - 3.0f * dot_uv * dot_vu) * chi3;

            const float* Qv = quad + 9 * v;
            float q00 = Qv[0], q01 = Qv[1], q02 = Qv[2];
            float q10 = Qv[3], q11 = Qv[4], q12 = Qv[5];
            float q20 = Qv[6], q21 = Qv[7], q22 = Qv[8];
            float s = vx * (vx * q00 + vy * q01 + vz * q02)
                    + vy * (vx * q10 + vy * q11 + vz * q12)
                    + vz * (vx * q20 + vy * q21 + vz * q22);
            float tr = q00 + q11 + q22;
            float n2 = vx * vx + vy * vy + vz * vz;
            float sum_uv = (s - n2 * (1.0f / 3.0f) * tr) * (inv_d * inv_d);

            Eelec += qu * sum_uv * chi3;
            res[k] = (d <= CUTOFF) ? (KEHALF * Eelec) : 0.0f;
        }
        *reinterpret_cast<float4*>(out + e0) =
            make_float4(res[0], res[1], res[2], res[3]);
    } else {
        // Scalar tail.
        for (int e = e0; e < E; ++e) {
            float d = dist[e];
            int u = idx_u[e], v = idx_v[e];
            float vx = vec[3 * e + 0], vy = vec[3 * e + 1], vz = vec[3 * e + 2];

            float inv_d = 1.0f / d;
            float x = fminf(fmaxf(d * 0.5f, 0.0f), 1.0f);
            float x2 = x * x;
            float x3 = x2 * x;
            float sw = 1.0f - x3 * (10.0f - 15.0f * x + 6.0f * x2);
            float chi = sw / sqrtf(d * d + 1.0f) + (1.0f - sw) * inv_d;
            float chi2 = chi * chi;
            float chi3 = chi2 * chi;

            float qu = q[u], qv = q[v];
            const float* mu_u = mu + 3 * u;
            const float* mu_v = mu + 3 * v;
            float dot_uv = (vx * mu_v[0] + vy * mu_v[1] + vz * mu_v[2]) * inv_d;
            float dot_vu = (vx * mu_u[0] + vy * mu_u[1] + vz * mu_u[2]) * inv_d;
            float mudot  = mu_u[0] * mu_v[0] + mu_u[1] * mu_v[1] + mu_u[2] * mu_v[2];

            float Eelec = qu * qv * chi
                        + 2.0f * qu * dot_uv * chi2
                        + (mudot - 3.0f * dot_uv * dot_vu) * chi3;

            const float* Qv = quad + 9 * v;
            float s = vx * (vx * Qv[0] + vy * Qv[1] + vz * Qv[2])
                    + vy * (vx * Qv[3] + vy * Qv[4] + vz * Qv[5])
                    + vz * (vx * Qv[6] + vy * Qv[7] + vz * Qv[8]);
            float tr = Qv[0] + Qv[4] + Qv[8];
            float n2 = vx * vx + vy * vy + vz * vz;
            float sum_uv = (s - n2 * (1.0f / 3.0f) * tr) * (inv_d * inv_d);

            Eelec += qu * sum_uv * chi3;
            out[e] = (d <= CUTOFF) ? (KEHALF * Eelec) : 0.0f;
        }
    }
}

extern "C" void kernel_launch(void* const* d_in, const int* in_sizes, int n_in,
                              void* d_out, int out_size, void* d_ws, size_t ws_size,
                              hipStream_t stream) {
    const float* dist  = (const float*)d_in[0];
    const float* vec   = (const float*)d_in[1];
    const float* q     = (const float*)d_in[2];
    const float* mu    = (const float*)d_in[3];
    const float* quad  = (const float*)d_in[4];
    const int*   idx_u = (const int*)d_in[5];
    const int*   idx_v = (const int*)d_in[6];
    float* out = (float*)d_out;

    int E = in_sizes[0];
    int threads = (E + 3) / 4;
    int block = 256;
    int grid = (threads + block - 1) / block;
    damped_elec_kernel<<<grid, block, 0, stream>>>(dist, vec, q, mu, quad,
                                                   idx_u, idx_v, out, E);
}